// Round 4
// baseline (530.499 us; speedup 1.0000x reference)
//
#include <hip/hip_runtime.h>
#include <math.h>

// Problem constants
constexpr int B_  = 128;
constexpr int S_  = 256;
constexpr int D_  = 128;   // d_model
constexpr int H_  = 8;
constexpr int DK_ = 16;
constexpr int SK_ = 30;    // SAMPLE_K
constexpr int NT_ = 30;    // N_TOP

typedef short short8  __attribute__((ext_vector_type(8)));
typedef float floatx4 __attribute__((ext_vector_type(4)));

__device__ inline ushort bf16_rne(float f) {
    unsigned u = __float_as_uint(f);
    u += 0x7fffu + ((u >> 16) & 1u);
    return (ushort)(u >> 16);
}
__device__ inline float bf16_to_f(ushort h) {
    return __uint_as_float(((unsigned)h) << 16);
}

// ---------------------------------------------------------------------------
// K0: W prep — conv weights (o,i,t) fp32 -> [t][o][i] bf16 hi/lo, plus
//  lin_w (e,c) fp32 -> bf16 hi/lo.
// ---------------------------------------------------------------------------
__global__ __launch_bounds__(256) void wprep_kernel(
    const float* __restrict__ wk, const float* __restrict__ wv,
    const float* __restrict__ lw,
    ushort* __restrict__ wk_hi, ushort* __restrict__ wk_lo,
    ushort* __restrict__ wv_hi,
    ushort* __restrict__ lw_hi, ushort* __restrict__ lw_lo)
{
    int tid = blockIdx.x * 256 + threadIdx.x;   // 0 .. 147455
    if (tid < 131072) {
        int which = tid >> 16;                  // 0 = k-conv, 1 = v-conv
        int oi = tid & 65535;                   // o*256 + i
        const float* src = (which ? wv : wk) + (size_t)oi * 7;
#pragma unroll
        for (int t = 0; t < 7; t++) {
            float f = src[t];
            ushort hi = bf16_rne(f);
            size_t dst = (size_t)t * 65536 + oi;
            if (which) {
                wv_hi[dst] = hi;
            } else {
                wk_hi[dst] = hi;
                wk_lo[dst] = bf16_rne(f - bf16_to_f(hi));
            }
        }
    } else {
        int ec = tid - 131072;                  // e*128 + c, 16384 elements
        float f = lw[ec];
        ushort hi = bf16_rne(f);
        lw_hi[ec] = hi;
        lw_lo[ec] = bf16_rne(f - bf16_to_f(hi));
    }
}

// ---------------------------------------------------------------------------
// K0b: rotary trig table (double precision, once per launch).
// ---------------------------------------------------------------------------
__global__ __launch_bounds__(256) void trig_kernel(float* __restrict__ tab)
{
    int tid = blockIdx.x * 256 + threadIdx.x;   // 0 .. 16383
    int f = tid & 63, l = tid >> 6;
    double freq = exp(((double)(-f) / 64.0) * 9.210340371976184); // ln(10000)
    double ang  = (double)l * freq;
    tab[tid * 2]     = (float)cos(ang);
    tab[tid * 2 + 1] = (float)sin(ang);
}

// ---------------------------------------------------------------------------
// K1: rotary — table lookup, memory-bound.
// ---------------------------------------------------------------------------
__global__ __launch_bounds__(256) void rotary_kernel(
    const float* __restrict__ q, const float* __restrict__ k,
    const float* __restrict__ tab,
    float* __restrict__ q_h, float* __restrict__ k_rot)
{
    int tid = blockIdx.x * 256 + threadIdx.x;   // over B*S*64
    int f = tid & 63;
    int l = (tid >> 6) & 255;
    int b = tid >> 14;

    float2 cs = *(const float2*)(tab + (size_t)(l * 64 + f) * 2);
    float c = cs.x, s = cs.y;

    int base = (b * S_ + l) * D_ + 2 * f;
    float q0 = q[base], q1 = q[base + 1];
    float k0 = k[base], k1 = k[base + 1];

    float qr = q0 * c - q1 * s;
    float qi = q0 * s + q1 * c;
    float kr = k0 * c - k1 * s;
    float ki = k0 * s + k1 * c;

    k_rot[base]     = kr;     // (B,S,D) — transcvt input
    k_rot[base + 1] = ki;

    int d = 2 * f;
    int h = d >> 4, dk = d & 15;
    int qb = ((b * H_ + h) * S_ + l) * DK_ + dk;
    q_h[qb]     = qr;         // (B,H,S,DK)
    q_h[qb + 1] = qi;
}

// ---------------------------------------------------------------------------
// K1b: transpose + bf16 hi/lo convert.
//  which=0: k_rot (B,S,D) fp32 -> khi_t, klo_t (B,D,S) bf16 pair.
//  which=1: value (B,S,D) fp32 -> vhi_t (B,D,S) bf16.
//  Same bf16_rne rounding as the old in-conv staging -> bit-identical k_h.
// ---------------------------------------------------------------------------
__global__ __launch_bounds__(256) void transcvt_kernel(
    const float* __restrict__ k_rot, const float* __restrict__ value,
    ushort* __restrict__ khi_t, ushort* __restrict__ klo_t,
    ushort* __restrict__ vhi_t)
{
    __shared__ float tile[64 * 132];   // 64 l x 128 d, pad 4
    int b = blockIdx.x;
    int which = blockIdx.y;            // 0 = k, 1 = v
    int tid = threadIdx.x;
    const float* src = which ? value : k_rot;

    for (int lc = 0; lc < 4; lc++) {
        __syncthreads();
        for (int s = tid; s < 2048; s += 256) {
            int l = s >> 5, c4 = s & 31;
            *(float4*)(tile + l * 132 + c4 * 4) =
                *(const float4*)(src + (((size_t)b * 256) + lc * 64 + l) * 128 + c4 * 4);
        }
        __syncthreads();
        int d = tid >> 1, half = tid & 1;
        alignas(16) ushort hh[32], ll[32];
#pragma unroll
        for (int j = 0; j < 32; j++) {
            float f = tile[(half * 32 + j) * 132 + d];
            ushort hb = bf16_rne(f);
            hh[j] = hb;
            ll[j] = bf16_rne(f - bf16_to_f(hb));
        }
        size_t off = (((size_t)b * 128) + d) * 256 + lc * 64 + half * 32;
        if (which) {
#pragma unroll
            for (int m = 0; m < 4; m++) ((uint4*)(vhi_t + off))[m] = ((uint4*)hh)[m];
        } else {
#pragma unroll
            for (int m = 0; m < 4; m++) ((uint4*)(khi_t + off))[m] = ((uint4*)hh)[m];
#pragma unroll
            for (int m = 0; m < 4; m++) ((uint4*)(klo_t + off))[m] = ((uint4*)ll)[m];
        }
    }
}

// ---------------------------------------------------------------------------
// K2: causal-conv-as-MFMA-GEMM, v2.  Y[o,d] = sum_{i,t} W[o,i,t]*X[i,d+t-6].
//  Input pre-transposed bf16 (B,D,S) -> staging is pure 16B copies.
//  Grid (b=128, oblk=4 [64 o], dblk=2 [64 d]) = 1024 blocks = 4 blocks/CU;
//  block = 4 waves, wave = 16 d x 64 o.  Per t-step per wave: 2 ds_read_b128
//  (hi+lo) + 8 global 16B (w) -> 12 MFMAs.  MFMA-bound per CU (~930 cyc vs
//  ~256 LDS cyc per (t,k32)); 16 waves/CU hides latency.
// ---------------------------------------------------------------------------
template<bool KP>
__global__ __launch_bounds__(256, 4) void conv2_kernel(
    const ushort* __restrict__ xhi_g, const ushort* __restrict__ xlo_g,
    const ushort* __restrict__ whi, const ushort* __restrict__ wlo,
    const float* __restrict__ bias, float* __restrict__ yh)
{
    constexpr int LI = 72;                 // 64 i + 8 pad (16B-aligned rows)
    __shared__ ushort xhi[70 * LI];
    __shared__ ushort xlo[KP ? 70 * LI : 8];

    int b   = blockIdx.x;
    int ob  = blockIdx.y * 64;
    int db  = blockIdx.z * 64;
    int tid = threadIdx.x;
    int lane = tid & 63, wid = tid >> 6;
    int lm = lane & 15, kb = lane >> 4;

    floatx4 acc[4];
#pragma unroll
    for (int i = 0; i < 4; i++) acc[i] = (floatx4){0.f, 0.f, 0.f, 0.f};

    const short8 zero8 = {0, 0, 0, 0, 0, 0, 0, 0};

    for (int ic = 0; ic < 4; ic++) {
        __syncthreads();
        // stage 70 rows (c = d-col, causal-shifted) x 64 i, 16B granules
        for (int s = tid; s < 560; s += 256) {
            int r = s >> 3, p = s & 7;
            int col = db - 6 + r;
            size_t goff = (((size_t)b * 128) + col) * 256 + ic * 64 + p * 8;
            short8 vh = (col >= 0) ? *(const short8*)(xhi_g + goff) : zero8;
            *(short8*)(xhi + r * LI + p * 8) = vh;
            if (KP) {
                short8 vl = (col >= 0) ? *(const short8*)(xlo_g + goff) : zero8;
                *(short8*)(xlo + r * LI + p * 8) = vl;
            }
        }
        __syncthreads();
#pragma unroll
        for (int ks2 = 0; ks2 < 2; ks2++) {
#pragma unroll
            for (int t = 0; t < 7; t++) {
                int arow = (wid * 16 + lm + t) * LI + ks2 * 32 + kb * 8;
                short8 ah = *(const short8*)(xhi + arow);
                short8 al;
                if (KP) al = *(const short8*)(xlo + arow);

                short8 bh[4], bl[4];
#pragma unroll
                for (int nf = 0; nf < 4; nf++) {
                    size_t woff = (size_t)t * 65536 + (size_t)(ob + nf * 16 + lm) * 256
                                + ic * 64 + ks2 * 32 + kb * 8;
                    bh[nf] = *(const short8*)(whi + woff);
                    if (KP) bl[nf] = *(const short8*)(wlo + woff);
                }
#pragma unroll
                for (int nf = 0; nf < 4; nf++) {
                    acc[nf] = __builtin_amdgcn_mfma_f32_16x16x32_bf16(ah, bh[nf], acc[nf], 0, 0, 0);
                    if (KP) {
                        acc[nf] = __builtin_amdgcn_mfma_f32_16x16x32_bf16(al, bh[nf], acc[nf], 0, 0, 0);
                        acc[nf] = __builtin_amdgcn_mfma_f32_16x16x32_bf16(ah, bl[nf], acc[nf], 0, 0, 0);
                    }
                }
            }
        }
    }

    // epilogue: D[row = m-local = kb*4+r][col = n-local = lm]
    int hidx = (db >> 4) + wid;
#pragma unroll
    for (int nf = 0; nf < 4; nf++) {
        int o = ob + nf * 16 + lm;
        float bv = bias[o];
#pragma unroll
        for (int r = 0; r < 4; r++) {
            int dk = kb * 4 + r;
            yh[(((size_t)b * 8 + hidx) * 256 + o) * 16 + dk] = acc[nf][r] + bv;
        }
    }
}

// ---------------------------------------------------------------------------
// K3: sampled scores, M = max - mean, stable top-30 by rank count (unchanged).
// ---------------------------------------------------------------------------
__global__ __launch_bounds__(256) void topk_kernel(
    const float* __restrict__ q_h, const float* __restrict__ k_h,
    const int* __restrict__ idxs, int* __restrict__ sel)
{
    __shared__ float ks[S_ * 20];
    __shared__ float Marr[S_];
    __shared__ int cnt;
    int bh  = blockIdx.x;
    int tid = threadIdx.x;
    if (tid == 0) cnt = 0;

    const float* kp = k_h + (size_t)bh * S_ * DK_;
    for (int idx = tid; idx < S_ * DK_; idx += 256)
        ks[(idx >> 4) * 20 + (idx & 15)] = kp[idx];
    __syncthreads();

    float qr[16];
    const float4* qp = (const float4*)(q_h + ((size_t)bh * S_ + tid) * DK_);
#pragma unroll
    for (int i = 0; i < 4; i++) {
        float4 t4 = qp[i];
        qr[4*i] = t4.x; qr[4*i+1] = t4.y; qr[4*i+2] = t4.z; qr[4*i+3] = t4.w;
    }
    int idxr[SK_];
    const int* ip = idxs + tid * SK_;
#pragma unroll
    for (int s = 0; s < SK_; s++) idxr[s] = ip[s];

    float mx = -1e30f, sm = 0.f;
#pragma unroll
    for (int s = 0; s < SK_; s++) {
        const float4* kr = (const float4*)(ks + idxr[s] * 20);
        float4 k0 = kr[0], k1 = kr[1], k2 = kr[2], k3 = kr[3];
        float d0 = qr[0]*k0.x, d1 = qr[1]*k0.y, d2 = qr[2]*k0.z, d3 = qr[3]*k0.w;
        d0 = fmaf(qr[4],  k1.x, d0); d1 = fmaf(qr[5],  k1.y, d1);
        d2 = fmaf(qr[6],  k1.z, d2); d3 = fmaf(qr[7],  k1.w, d3);
        d0 = fmaf(qr[8],  k2.x, d0); d1 = fmaf(qr[9],  k2.y, d1);
        d2 = fmaf(qr[10], k2.z, d2); d3 = fmaf(qr[11], k2.w, d3);
        d0 = fmaf(qr[12], k3.x, d0); d1 = fmaf(qr[13], k3.y, d1);
        d2 = fmaf(qr[14], k3.z, d2); d3 = fmaf(qr[15], k3.w, d3);
        float dot = (d0 + d1) + (d2 + d3);
        mx = fmaxf(mx, dot);
        sm += dot;
    }
    float M = mx - sm * (1.0f / 30.0f);
    Marr[tid] = M;
    __syncthreads();

    int higher = 0;
    for (int j = 0; j < S_; j++) {
        float Mj = Marr[j];
        if (Mj > M || (Mj == M && j < tid)) higher++;
    }
    if (higher < NT_) {
        int slot = atomicAdd(&cnt, 1);
        sel[bh * NT_ + slot] = tid;
    }
}

// ---------------------------------------------------------------------------
// K4: attention + context assembly (unchanged; ctx as bf16 hi/lo).
// ---------------------------------------------------------------------------
__global__ __launch_bounds__(256) void attn_kernel(
    const float* __restrict__ q_h, const float* __restrict__ k_h,
    const float* __restrict__ v_h, const int* __restrict__ sel,
    ushort* __restrict__ ctx_hi, ushort* __restrict__ ctx_lo)
{
    __shared__ float ks[S_ * 20];
    __shared__ float vs[S_ * 20];
    __shared__ float P[NT_][S_ + 1];
    __shared__ float qs[NT_][16];
    __shared__ float partial[16][17];
    __shared__ float vmean_s[16];
    __shared__ int sel_s[NT_];
    __shared__ int selflag[S_];

    int bh = blockIdx.x, b = bh >> 3, h = bh & 7;
    int tid = threadIdx.x;

    const float* kp = k_h + (size_t)bh * S_ * DK_;
    const float* vp = v_h + (size_t)bh * S_ * DK_;
    for (int idx = tid; idx < S_ * DK_; idx += 256) {
        int r = idx >> 4, c = idx & 15;
        ks[r * 20 + c] = kp[idx];
        vs[r * 20 + c] = vp[idx];
    }
    selflag[tid] = 0;
    if (tid < NT_) sel_s[tid] = sel[bh * NT_ + tid];
    __syncthreads();
    if (tid < NT_) selflag[sel_s[tid]] = 1;
    for (int idx = tid; idx < NT_ * 16; idx += 256) {
        int u = idx >> 4, c = idx & 15;
        qs[u][c] = q_h[((size_t)bh * S_ + sel_s[u]) * DK_ + c];
    }
    {
        int dk = tid & 15, chunk = tid >> 4;
        float s = 0.f;
#pragma unroll
        for (int r = 0; r < 16; r++) s += vs[(chunk * 16 + r) * 20 + dk];
        partial[chunk][dk] = s;
    }
    __syncthreads();
    if (tid < 16) {
        float s = 0.f;
#pragma unroll
        for (int c = 0; c < 16; c++) s += partial[c][tid];
        vmean_s[tid] = s * (1.0f / 256.0f);
    }
    __syncthreads();

    if (!selflag[tid]) {
        alignas(16) ushort hh[16], ll[16];
#pragma unroll
        for (int i = 0; i < 16; i++) {
            float v = vmean_s[i];
            ushort hb = bf16_rne(v);
            hh[i] = hb;
            ll[i] = bf16_rne(v - bf16_to_f(hb));
        }
        size_t off = ((size_t)(b * S_ + tid)) * D_ + h * DK_;
        ((uint4*)(ctx_hi + off))[0] = ((uint4*)hh)[0];
        ((uint4*)(ctx_hi + off))[1] = ((uint4*)hh)[1];
        ((uint4*)(ctx_lo + off))[0] = ((uint4*)ll)[0];
        ((uint4*)(ctx_lo + off))[1] = ((uint4*)ll)[1];
    }

    int g = tid >> 3, j = tid & 7;
    if (g < NT_) {
        float qreg[16];
        const float4* q4 = (const float4*)qs[g];
#pragma unroll
        for (int i = 0; i < 4; i++) {
            float4 t4 = q4[i];
            qreg[4*i] = t4.x; qreg[4*i+1] = t4.y; qreg[4*i+2] = t4.z; qreg[4*i+3] = t4.w;
        }
        float sc[32];
        float mx = -1e30f;
#pragma unroll
        for (int li = 0; li < 32; li++) {
            int l = j + li * 8;
            const float4* kr = (const float4*)(ks + l * 20);
            float4 k0 = kr[0], k1 = kr[1], k2 = kr[2], k3 = kr[3];
            float d0 = qreg[0]*k0.x, d1 = qreg[1]*k0.y, d2 = qreg[2]*k0.z, d3 = qreg[3]*k0.w;
            d0 = fmaf(qreg[4],  k1.x, d0); d1 = fmaf(qreg[5],  k1.y, d1);
            d2 = fmaf(qreg[6],  k1.z, d2); d3 = fmaf(qreg[7],  k1.w, d3);
            d0 = fmaf(qreg[8],  k2.x, d0); d1 = fmaf(qreg[9],  k2.y, d1);
            d2 = fmaf(qreg[10], k2.z, d2); d3 = fmaf(qreg[11], k2.w, d3);
            d0 = fmaf(qreg[12], k3.x, d0); d1 = fmaf(qreg[13], k3.y, d1);
            d2 = fmaf(qreg[14], k3.z, d2); d3 = fmaf(qreg[15], k3.w, d3);
            sc[li] = ((d0 + d1) + (d2 + d3)) * 0.25f;
            mx = fmaxf(mx, sc[li]);
        }
        mx = fmaxf(mx, __shfl_xor(mx, 1));
        mx = fmaxf(mx, __shfl_xor(mx, 2));
        mx = fmaxf(mx, __shfl_xor(mx, 4));
        float se = 0.f;
#pragma unroll
        for (int li = 0; li < 32; li++) {
            float e = __expf(sc[li] - mx);
            P[g][j + li * 8] = e;
            se += e;
        }
        se += __shfl_xor(se, 1);
        se += __shfl_xor(se, 2);
        se += __shfl_xor(se, 4);
        float inv = 1.0f / se;

        int dk0 = j * 2;
        float o0 = 0.f, o1 = 0.f;
#pragma unroll 8
        for (int l = 0; l < S_; l++) {
            float p = P[g][l];
            float2 vv = *(const float2*)(vs + l * 20 + dk0);
            o0 = fmaf(p, vv.x, o0);
            o1 = fmaf(p, vv.y, o1);
        }
        int lrow = sel_s[g];
        float v0 = o0 * inv, v1 = o1 * inv;
        ushort h0 = bf16_rne(v0), h1 = bf16_rne(v1);
        ushort l0 = bf16_rne(v0 - bf16_to_f(h0));
        ushort l1 = bf16_rne(v1 - bf16_to_f(h1));
        size_t off = ((size_t)(b * S_ + lrow)) * D_ + h * DK_ + dk0;
        *(uint*)(ctx_hi + off) = (uint)h0 | ((uint)h1 << 16);
        *(uint*)(ctx_lo + off) = (uint)l0 | ((uint)l1 << 16);
    }
}

// ---------------------------------------------------------------------------
// K5: final linear as MFMA GEMM (unchanged).
// ---------------------------------------------------------------------------
__global__ __launch_bounds__(256) void linear_mfma_kernel(
    const ushort* __restrict__ ctx_hi, const ushort* __restrict__ ctx_lo,
    const ushort* __restrict__ w_hi, const ushort* __restrict__ w_lo,
    const float* __restrict__ bias, float* __restrict__ out)
{
    __shared__ ushort ahi[128 * 136];
    __shared__ ushort alo[128 * 136];

    int tid  = threadIdx.x;
    int lane = tid & 63, wid = tid >> 6;
    int lm = lane & 15, kb = lane >> 4;
    size_t rowbase = (size_t)blockIdx.x * 128;

    for (int idx = tid; idx < 2048; idx += 256) {
        int row = idx >> 4, c16 = idx & 15;
        short8 vh = *(const short8*)(ctx_hi + (rowbase + row) * 128 + c16 * 8);
        short8 vl = *(const short8*)(ctx_lo + (rowbase + row) * 128 + c16 * 8);
        *(short8*)(ahi + row * 136 + c16 * 8) = vh;
        *(short8*)(alo + row * 136 + c16 * 8) = vl;
    }
    __syncthreads();

    floatx4 acc[16];
#pragma unroll
    for (int i = 0; i < 16; i++) acc[i] = (floatx4){0.f, 0.f, 0.f, 0.f};

    const ushort* arow_h = ahi + (wid * 32 + lm) * 136 + kb * 8;
    const ushort* arow_l = alo + (wid * 32 + lm) * 136 + kb * 8;

#pragma unroll
    for (int kstep = 0; kstep < 4; kstep++) {
        short8 afh[2], afl[2];
#pragma unroll
        for (int mf = 0; mf < 2; mf++) {
            afh[mf] = *(const short8*)(arow_h + mf * 16 * 136 + kstep * 32);
            afl[mf] = *(const short8*)(arow_l + mf * 16 * 136 + kstep * 32);
        }
        short8 bfh[8], bfl[8];
#pragma unroll
        for (int nf = 0; nf < 8; nf++) {
            bfh[nf] = *(const short8*)(w_hi + (size_t)(nf * 16 + lm) * 128 + kstep * 32 + kb * 8);
            bfl[nf] = *(const short8*)(w_lo + (size_t)(nf * 16 + lm) * 128 + kstep * 32 + kb * 8);
        }
#pragma unroll
        for (int mf = 0; mf < 2; mf++) {
#pragma unroll
            for (int nf = 0; nf < 8; nf++) {
                int a = mf * 8 + nf;
                acc[a] = __builtin_amdgcn_mfma_f32_16x16x32_bf16(afh[mf], bfh[nf], acc[a], 0, 0, 0);
                acc[a] = __builtin_amdgcn_mfma_f32_16x16x32_bf16(afl[mf], bfh[nf], acc[a], 0, 0, 0);
                acc[a] = __builtin_amdgcn_mfma_f32_16x16x32_bf16(afh[mf], bfl[nf], acc[a], 0, 0, 0);
            }
        }
    }

#pragma unroll
    for (int nf = 0; nf < 8; nf++) {
        int col = nf * 16 + lm;
        float bv = bias[col];
#pragma unroll
        for (int mf = 0; mf < 2; mf++) {
#pragma unroll
            for (int r = 0; r < 4; r++) {
                int row = wid * 32 + mf * 16 + kb * 4 + r;
                out[(rowbase + row) * 128 + col] = acc[mf * 8 + nf][r] + bv;
            }
        }
    }
}

// ---------------------------------------------------------------------------
extern "C" void kernel_launch(void* const* d_in, const int* in_sizes, int n_in,
                              void* d_out, int out_size, void* d_ws, size_t ws_size,
                              hipStream_t stream)
{
    const float* query = (const float*)d_in[0];
    const float* key   = (const float*)d_in[1];
    const float* value = (const float*)d_in[2];
    const float* ckw   = (const float*)d_in[3];
    const float* ckb   = (const float*)d_in[4];
    const float* cvw   = (const float*)d_in[5];
    const float* cvb   = (const float*)d_in[6];
    const float* lw    = (const float*)d_in[7];
    const float* lb    = (const float*)d_in[8];
    const int*   isamp = (const int*)d_in[9];
    float* out = (float*)d_out;
    float* ws  = (float*)d_ws;

    const size_t NBSD = (size_t)B_ * S_ * D_;   // 4,194,304 floats
    float* q_h  = ws;                   // (B,H,S,DK)
    float* kbuf = ws + NBSD;            // k_rot (B,S,D); overlaid by ctx hi/lo
    float* k_h  = ws + 2 * NBSD;        // (B,H,S,DK)
    float* v_h  = ws + 3 * NBSD;        // (B,H,S,DK)
    int*   sel  = (int*)(ws + 4 * NBSD);        // (B*H, 30)
    ushort* wk_hi = (ushort*)(sel + B_ * H_ * NT_);   // [7][256][256] bf16 each
    ushort* wk_lo = wk_hi + 7 * 65536;
    ushort* wv_hi = wk_lo + 7 * 65536;
    ushort* lw_hi = wv_hi + 7 * 65536;  // [128][128]
    ushort* lw_lo = lw_hi + 16384;
    float*  trig  = (float*)(lw_lo + 16384);    // [256][64][2]
    ushort* khi_t = (ushort*)(trig + 32768);    // (B,D,S) bf16
    ushort* klo_t = khi_t + NBSD;
    ushort* vhi_t = klo_t + NBSD;
    // ctx hi/lo overlay kbuf (free after transcvt+conv)
    ushort* ctx_hi = (ushort*)kbuf;
    ushort* ctx_lo = ctx_hi + NBSD;

    wprep_kernel<<<dim3(576), 256, 0, stream>>>(ckw, cvw, lw, wk_hi, wk_lo, wv_hi, lw_hi, lw_lo);
    trig_kernel<<<dim3(64), 256, 0, stream>>>(trig);
    rotary_kernel<<<dim3((B_ * S_ * 64) / 256), 256, 0, stream>>>(query, key, trig, q_h, kbuf);
    transcvt_kernel<<<dim3(B_, 2), 256, 0, stream>>>(kbuf, value, khi_t, klo_t, vhi_t);
    conv2_kernel<true ><<<dim3(B_, 4, 2), 256, 0, stream>>>(khi_t, klo_t, wk_hi, wk_lo, ckb, k_h);
    conv2_kernel<false><<<dim3(B_, 4, 2), 256, 0, stream>>>(vhi_t, vhi_t, wv_hi, wv_hi, cvb, v_h);
    topk_kernel<<<dim3(B_ * H_), 256, 0, stream>>>(q_h, k_h, isamp, sel);
    attn_kernel<<<dim3(B_ * H_), 256, 0, stream>>>(q_h, k_h, v_h, sel, ctx_hi, ctx_lo);
    linear_mfma_kernel<<<dim3(256), 256, 0, stream>>>(ctx_hi, ctx_lo, lw_hi, lw_lo, lb, out);
}

// Round 5
// 284.482 us; speedup vs baseline: 1.8648x; 1.8648x over previous
//
#include <hip/hip_runtime.h>
#include <math.h>

// Problem constants
constexpr int B_  = 128;
constexpr int S_  = 256;
constexpr int D_  = 128;   // d_model
constexpr int H_  = 8;
constexpr int DK_ = 16;
constexpr int SK_ = 30;    // SAMPLE_K
constexpr int NT_ = 30;    // N_TOP

typedef short short8  __attribute__((ext_vector_type(8)));
typedef float floatx4 __attribute__((ext_vector_type(4)));

__device__ inline ushort bf16_rne(float f) {
    unsigned u = __float_as_uint(f);
    u += 0x7fffu + ((u >> 16) & 1u);
    return (ushort)(u >> 16);
}
__device__ inline float bf16_to_f(ushort h) {
    return __uint_as_float(((unsigned)h) << 16);
}

// ---------------------------------------------------------------------------
// K0: W prep — conv weights (o,i,t) fp32 -> [t][o][i] bf16 hi/lo, plus
//  lin_w (e,c) fp32 -> bf16 hi/lo.
// ---------------------------------------------------------------------------
__global__ __launch_bounds__(256) void wprep_kernel(
    const float* __restrict__ wk, const float* __restrict__ wv,
    const float* __restrict__ lw,
    ushort* __restrict__ wk_hi, ushort* __restrict__ wk_lo,
    ushort* __restrict__ wv_hi,
    ushort* __restrict__ lw_hi, ushort* __restrict__ lw_lo)
{
    int tid = blockIdx.x * 256 + threadIdx.x;   // 0 .. 147455
    if (tid < 131072) {
        int which = tid >> 16;                  // 0 = k-conv, 1 = v-conv
        int oi = tid & 65535;                   // o*256 + i
        const float* src = (which ? wv : wk) + (size_t)oi * 7;
#pragma unroll
        for (int t = 0; t < 7; t++) {
            float f = src[t];
            ushort hi = bf16_rne(f);
            size_t dst = (size_t)t * 65536 + oi;
            if (which) {
                wv_hi[dst] = hi;
            } else {
                wk_hi[dst] = hi;
                wk_lo[dst] = bf16_rne(f - bf16_to_f(hi));
            }
        }
    } else {
        int ec = tid - 131072;                  // e*128 + c, 16384 elements
        float f = lw[ec];
        ushort hi = bf16_rne(f);
        lw_hi[ec] = hi;
        lw_lo[ec] = bf16_rne(f - bf16_to_f(hi));
    }
}

// ---------------------------------------------------------------------------
// K0b: rotary trig table (double precision, once per launch).
// ---------------------------------------------------------------------------
__global__ __launch_bounds__(256) void trig_kernel(float* __restrict__ tab)
{
    int tid = blockIdx.x * 256 + threadIdx.x;   // 0 .. 16383
    int f = tid & 63, l = tid >> 6;
    double freq = exp(((double)(-f) / 64.0) * 9.210340371976184); // ln(10000)
    double ang  = (double)l * freq;
    tab[tid * 2]     = (float)cos(ang);
    tab[tid * 2 + 1] = (float)sin(ang);
}

// ---------------------------------------------------------------------------
// K1: rotary — table lookup, memory-bound.
// ---------------------------------------------------------------------------
__global__ __launch_bounds__(256) void rotary_kernel(
    const float* __restrict__ q, const float* __restrict__ k,
    const float* __restrict__ tab,
    float* __restrict__ q_h, float* __restrict__ k_rot)
{
    int tid = blockIdx.x * 256 + threadIdx.x;   // over B*S*64
    int f = tid & 63;
    int l = (tid >> 6) & 255;
    int b = tid >> 14;

    float2 cs = *(const float2*)(tab + (size_t)(l * 64 + f) * 2);
    float c = cs.x, s = cs.y;

    int base = (b * S_ + l) * D_ + 2 * f;
    float q0 = q[base], q1 = q[base + 1];
    float k0 = k[base], k1 = k[base + 1];

    float qr = q0 * c - q1 * s;
    float qi = q0 * s + q1 * c;
    float kr = k0 * c - k1 * s;
    float ki = k0 * s + k1 * c;

    k_rot[base]     = kr;     // (B,S,D) — transcvt input
    k_rot[base + 1] = ki;

    int d = 2 * f;
    int h = d >> 4, dk = d & 15;
    int qb = ((b * H_ + h) * S_ + l) * DK_ + dk;
    q_h[qb]     = qr;         // (B,H,S,DK)
    q_h[qb + 1] = qi;
}

// ---------------------------------------------------------------------------
// K1b: transpose + bf16 hi/lo convert.
//  which=0: k_rot (B,S,D) fp32 -> khi_t, klo_t (B,D,S) bf16 pair.
//  which=1: value (B,S,D) fp32 -> vhi_t (B,D,S) bf16.
// ---------------------------------------------------------------------------
__global__ __launch_bounds__(256) void transcvt_kernel(
    const float* __restrict__ k_rot, const float* __restrict__ value,
    ushort* __restrict__ khi_t, ushort* __restrict__ klo_t,
    ushort* __restrict__ vhi_t)
{
    __shared__ float tile[64 * 132];   // 64 l x 128 d, pad 4
    int b = blockIdx.x;
    int which = blockIdx.y;            // 0 = k, 1 = v
    int tid = threadIdx.x;
    const float* src = which ? value : k_rot;

    for (int lc = 0; lc < 4; lc++) {
        __syncthreads();
        for (int s = tid; s < 2048; s += 256) {
            int l = s >> 5, c4 = s & 31;
            *(float4*)(tile + l * 132 + c4 * 4) =
                *(const float4*)(src + (((size_t)b * 256) + lc * 64 + l) * 128 + c4 * 4);
        }
        __syncthreads();
        int d = tid >> 1, half = tid & 1;
        alignas(16) ushort hh[32], ll[32];
#pragma unroll
        for (int j = 0; j < 32; j++) {
            float f = tile[(half * 32 + j) * 132 + d];
            ushort hb = bf16_rne(f);
            hh[j] = hb;
            ll[j] = bf16_rne(f - bf16_to_f(hb));
        }
        size_t off = (((size_t)b * 128) + d) * 256 + lc * 64 + half * 32;
        if (which) {
#pragma unroll
            for (int m = 0; m < 4; m++) ((uint4*)(vhi_t + off))[m] = ((uint4*)hh)[m];
        } else {
#pragma unroll
            for (int m = 0; m < 4; m++) ((uint4*)(khi_t + off))[m] = ((uint4*)hh)[m];
#pragma unroll
            for (int m = 0; m < 4; m++) ((uint4*)(klo_t + off))[m] = ((uint4*)ll)[m];
        }
    }
}

// ---------------------------------------------------------------------------
// K2: fused causal-conv-as-MFMA-GEMM (k + v in one dispatch).
//  R3's proven tiling: block = 64o x 128d, 4 waves 2x2, wave = 32o x 64d,
//  per (ks2,t): 8 LDS b128 + 8 global 16B -> 24 MFMAs (k) / 8 (v).
//  Input pre-transposed bf16 (B,D,S): staging = pure 16B copies (no VALU
//  convert, x read once per block).  blockIdx.z picks k/v (wave-uniform).
//  Grid 128x4x2 = 1024 blocks, LDS 38.6 KB -> 4 blocks/CU, 16 waves/CU.
//  Accumulation order (ic->ks2->t, hh/lh/hl) identical to R3/R4 -> k_h
//  bitwise unchanged -> top-k selection stable.
// ---------------------------------------------------------------------------
__global__ __launch_bounds__(256, 4) void conv3_kernel(
    const ushort* __restrict__ khi_t, const ushort* __restrict__ klo_t,
    const ushort* __restrict__ vhi_t,
    const ushort* __restrict__ wk_hi, const ushort* __restrict__ wk_lo,
    const ushort* __restrict__ wv_hi,
    const float* __restrict__ kbias, const float* __restrict__ vbias,
    float* __restrict__ k_h, float* __restrict__ v_h)
{
    constexpr int LI = 72;                 // 64 i + 8 pad (16B-aligned rows)
    __shared__ ushort xhi[134 * LI];
    __shared__ ushort xlo[134 * LI];

    const bool kp = (blockIdx.z == 0);
    const ushort* xhi_g = kp ? khi_t : vhi_t;
    const ushort* whi   = kp ? wk_hi : wv_hi;
    const float*  bias  = kp ? kbias : vbias;
    float* yh           = kp ? k_h : v_h;

    int b    = blockIdx.x;
    int oblk = blockIdx.y * 64;
    int tid  = threadIdx.x;
    int lane = tid & 63, wid = tid >> 6;
    int lm = lane & 15, kb = lane >> 4;
    int ow = wid >> 1, dw = wid & 1;
    int obase = oblk + ow * 32;
    int dbase = dw * 64;

    floatx4 acc[8];
#pragma unroll
    for (int i = 0; i < 8; i++) acc[i] = (floatx4){0.f, 0.f, 0.f, 0.f};

    // causal left pad (rows c<6 i.e. d<0): zero once, valid for all ic
    for (int idx = tid; idx < 6 * LI; idx += 256) { xhi[idx] = 0; xlo[idx] = 0; }

    const ushort* abase_h = xhi + (dbase + lm) * LI + kb * 8;
    const ushort* abase_l = xlo + (dbase + lm) * LI + kb * 8;

    for (int ic = 0; ic < 4; ic++) {
        __syncthreads();
        // stage 128 d-rows x 64 i: pure 16B copies from (B,D,S) layout
        for (int s = tid; s < 1024; s += 256) {
            int d = s >> 3, p = s & 7;
            size_t g = (((size_t)b * 128) + d) * 256 + ic * 64 + p * 8;
            *(short8*)(xhi + (d + 6) * LI + p * 8) = *(const short8*)(xhi_g + g);
            if (kp)
                *(short8*)(xlo + (d + 6) * LI + p * 8) = *(const short8*)(klo_t + g);
        }
        __syncthreads();
#pragma unroll
        for (int ks2 = 0; ks2 < 2; ks2++) {
            int ibase = ic * 64 + ks2 * 32 + kb * 8;
#pragma unroll
            for (int t = 0; t < 7; t++) {
                short8 xh[4], xl[4];
#pragma unroll
                for (int nd = 0; nd < 4; nd++) {
                    xh[nd] = *(const short8*)(abase_h + (nd * 16 + t) * LI + ks2 * 32);
                    if (kp) xl[nd] = *(const short8*)(abase_l + (nd * 16 + t) * LI + ks2 * 32);
                }
                short8 wh[2], wl[2];
#pragma unroll
                for (int po = 0; po < 2; po++) {
                    size_t woff = (size_t)t * 65536 + (size_t)(obase + po * 16 + lm) * 256 + ibase;
                    wh[po] = *(const short8*)(whi + woff);
                    if (kp) wl[po] = *(const short8*)(wk_lo + woff);
                }
#pragma unroll
                for (int po = 0; po < 2; po++) {
#pragma unroll
                    for (int nd = 0; nd < 4; nd++) {
                        int a = po * 4 + nd;
                        acc[a] = __builtin_amdgcn_mfma_f32_16x16x32_bf16(xh[nd], wh[po], acc[a], 0, 0, 0);
                        if (kp) {
                            acc[a] = __builtin_amdgcn_mfma_f32_16x16x32_bf16(xl[nd], wh[po], acc[a], 0, 0, 0);
                            acc[a] = __builtin_amdgcn_mfma_f32_16x16x32_bf16(xh[nd], wl[po], acc[a], 0, 0, 0);
                        }
                    }
                }
            }
        }
    }

    // epilogue: D[m=d][n=o]; row = kb*4+r -> d-local, col = lm -> o-local
#pragma unroll
    for (int po = 0; po < 2; po++) {
        int o = obase + po * 16 + lm;
        float bv = bias[o];
#pragma unroll
        for (int nd = 0; nd < 4; nd++) {
            int dhi = dw * 4 + nd;   // d>>4
#pragma unroll
            for (int r = 0; r < 4; r++) {
                int dk = kb * 4 + r;
                yh[(((size_t)b * 8 + dhi) * 256 + o) * 16 + dk] = acc[po * 4 + nd][r] + bv;
            }
        }
    }
}

// ---------------------------------------------------------------------------
// K3: sampled scores, M = max - mean, stable top-30 by rank count (unchanged).
// ---------------------------------------------------------------------------
__global__ __launch_bounds__(256) void topk_kernel(
    const float* __restrict__ q_h, const float* __restrict__ k_h,
    const int* __restrict__ idxs, int* __restrict__ sel)
{
    __shared__ float ks[S_ * 20];
    __shared__ float Marr[S_];
    __shared__ int cnt;
    int bh  = blockIdx.x;
    int tid = threadIdx.x;
    if (tid == 0) cnt = 0;

    const float* kp = k_h + (size_t)bh * S_ * DK_;
    for (int idx = tid; idx < S_ * DK_; idx += 256)
        ks[(idx >> 4) * 20 + (idx & 15)] = kp[idx];
    __syncthreads();

    float qr[16];
    const float4* qp = (const float4*)(q_h + ((size_t)bh * S_ + tid) * DK_);
#pragma unroll
    for (int i = 0; i < 4; i++) {
        float4 t4 = qp[i];
        qr[4*i] = t4.x; qr[4*i+1] = t4.y; qr[4*i+2] = t4.z; qr[4*i+3] = t4.w;
    }
    int idxr[SK_];
    const int* ip = idxs + tid * SK_;
#pragma unroll
    for (int s = 0; s < SK_; s++) idxr[s] = ip[s];

    float mx = -1e30f, sm = 0.f;
#pragma unroll
    for (int s = 0; s < SK_; s++) {
        const float4* kr = (const float4*)(ks + idxr[s] * 20);
        float4 k0 = kr[0], k1 = kr[1], k2 = kr[2], k3 = kr[3];
        float d0 = qr[0]*k0.x, d1 = qr[1]*k0.y, d2 = qr[2]*k0.z, d3 = qr[3]*k0.w;
        d0 = fmaf(qr[4],  k1.x, d0); d1 = fmaf(qr[5],  k1.y, d1);
        d2 = fmaf(qr[6],  k1.z, d2); d3 = fmaf(qr[7],  k1.w, d3);
        d0 = fmaf(qr[8],  k2.x, d0); d1 = fmaf(qr[9],  k2.y, d1);
        d2 = fmaf(qr[10], k2.z, d2); d3 = fmaf(qr[11], k2.w, d3);
        d0 = fmaf(qr[12], k3.x, d0); d1 = fmaf(qr[13], k3.y, d1);
        d2 = fmaf(qr[14], k3.z, d2); d3 = fmaf(qr[15], k3.w, d3);
        float dot = (d0 + d1) + (d2 + d3);
        mx = fmaxf(mx, dot);
        sm += dot;
    }
    float M = mx - sm * (1.0f / 30.0f);
    Marr[tid] = M;
    __syncthreads();

    int higher = 0;
    for (int j = 0; j < S_; j++) {
        float Mj = Marr[j];
        if (Mj > M || (Mj == M && j < tid)) higher++;
    }
    if (higher < NT_) {
        int slot = atomicAdd(&cnt, 1);
        sel[bh * NT_ + slot] = tid;
    }
}

// ---------------------------------------------------------------------------
// K4: attention + context assembly (unchanged; ctx as bf16 hi/lo).
// ---------------------------------------------------------------------------
__global__ __launch_bounds__(256) void attn_kernel(
    const float* __restrict__ q_h, const float* __restrict__ k_h,
    const float* __restrict__ v_h, const int* __restrict__ sel,
    ushort* __restrict__ ctx_hi, ushort* __restrict__ ctx_lo)
{
    __shared__ float ks[S_ * 20];
    __shared__ float vs[S_ * 20];
    __shared__ float P[NT_][S_ + 1];
    __shared__ float qs[NT_][16];
    __shared__ float partial[16][17];
    __shared__ float vmean_s[16];
    __shared__ int sel_s[NT_];
    __shared__ int selflag[S_];

    int bh = blockIdx.x, b = bh >> 3, h = bh & 7;
    int tid = threadIdx.x;

    const float* kp = k_h + (size_t)bh * S_ * DK_;
    const float* vp = v_h + (size_t)bh * S_ * DK_;
    for (int idx = tid; idx < S_ * DK_; idx += 256) {
        int r = idx >> 4, c = idx & 15;
        ks[r * 20 + c] = kp[idx];
        vs[r * 20 + c] = vp[idx];
    }
    selflag[tid] = 0;
    if (tid < NT_) sel_s[tid] = sel[bh * NT_ + tid];
    __syncthreads();
    if (tid < NT_) selflag[sel_s[tid]] = 1;
    for (int idx = tid; idx < NT_ * 16; idx += 256) {
        int u = idx >> 4, c = idx & 15;
        qs[u][c] = q_h[((size_t)bh * S_ + sel_s[u]) * DK_ + c];
    }
    {
        int dk = tid & 15, chunk = tid >> 4;
        float s = 0.f;
#pragma unroll
        for (int r = 0; r < 16; r++) s += vs[(chunk * 16 + r) * 20 + dk];
        partial[chunk][dk] = s;
    }
    __syncthreads();
    if (tid < 16) {
        float s = 0.f;
#pragma unroll
        for (int c = 0; c < 16; c++) s += partial[c][tid];
        vmean_s[tid] = s * (1.0f / 256.0f);
    }
    __syncthreads();

    if (!selflag[tid]) {
        alignas(16) ushort hh[16], ll[16];
#pragma unroll
        for (int i = 0; i < 16; i++) {
            float v = vmean_s[i];
            ushort hb = bf16_rne(v);
            hh[i] = hb;
            ll[i] = bf16_rne(v - bf16_to_f(hb));
        }
        size_t off = ((size_t)(b * S_ + tid)) * D_ + h * DK_;
        ((uint4*)(ctx_hi + off))[0] = ((uint4*)hh)[0];
        ((uint4*)(ctx_hi + off))[1] = ((uint4*)hh)[1];
        ((uint4*)(ctx_lo + off))[0] = ((uint4*)ll)[0];
        ((uint4*)(ctx_lo + off))[1] = ((uint4*)ll)[1];
    }

    int g = tid >> 3, j = tid & 7;
    if (g < NT_) {
        float qreg[16];
        const float4* q4 = (const float4*)qs[g];
#pragma unroll
        for (int i = 0; i < 4; i++) {
            float4 t4 = q4[i];
            qreg[4*i] = t4.x; qreg[4*i+1] = t4.y; qreg[4*i+2] = t4.z; qreg[4*i+3] = t4.w;
        }
        float sc[32];
        float mx = -1e30f;
#pragma unroll
        for (int li = 0; li < 32; li++) {
            int l = j + li * 8;
            const float4* kr = (const float4*)(ks + l * 20);
            float4 k0 = kr[0], k1 = kr[1], k2 = kr[2], k3 = kr[3];
            float d0 = qreg[0]*k0.x, d1 = qreg[1]*k0.y, d2 = qreg[2]*k0.z, d3 = qreg[3]*k0.w;
            d0 = fmaf(qreg[4],  k1.x, d0); d1 = fmaf(qreg[5],  k1.y, d1);
            d2 = fmaf(qreg[6],  k1.z, d2); d3 = fmaf(qreg[7],  k1.w, d3);
            d0 = fmaf(qreg[8],  k2.x, d0); d1 = fmaf(qreg[9],  k2.y, d1);
            d2 = fmaf(qreg[10], k2.z, d2); d3 = fmaf(qreg[11], k2.w, d3);
            d0 = fmaf(qreg[12], k3.x, d0); d1 = fmaf(qreg[13], k3.y, d1);
            d2 = fmaf(qreg[14], k3.z, d2); d3 = fmaf(qreg[15], k3.w, d3);
            sc[li] = ((d0 + d1) + (d2 + d3)) * 0.25f;
            mx = fmaxf(mx, sc[li]);
        }
        mx = fmaxf(mx, __shfl_xor(mx, 1));
        mx = fmaxf(mx, __shfl_xor(mx, 2));
        mx = fmaxf(mx, __shfl_xor(mx, 4));
        float se = 0.f;
#pragma unroll
        for (int li = 0; li < 32; li++) {
            float e = __expf(sc[li] - mx);
            P[g][j + li * 8] = e;
            se += e;
        }
        se += __shfl_xor(se, 1);
        se += __shfl_xor(se, 2);
        se += __shfl_xor(se, 4);
        float inv = 1.0f / se;

        int dk0 = j * 2;
        float o0 = 0.f, o1 = 0.f;
#pragma unroll 8
        for (int l = 0; l < S_; l++) {
            float p = P[g][l];
            float2 vv = *(const float2*)(vs + l * 20 + dk0);
            o0 = fmaf(p, vv.x, o0);
            o1 = fmaf(p, vv.y, o1);
        }
        int lrow = sel_s[g];
        float v0 = o0 * inv, v1 = o1 * inv;
        ushort h0 = bf16_rne(v0), h1 = bf16_rne(v1);
        ushort l0 = bf16_rne(v0 - bf16_to_f(h0));
        ushort l1 = bf16_rne(v1 - bf16_to_f(h1));
        size_t off = ((size_t)(b * S_ + lrow)) * D_ + h * DK_ + dk0;
        *(uint*)(ctx_hi + off) = (uint)h0 | ((uint)h1 << 16);
        *(uint*)(ctx_lo + off) = (uint)l0 | ((uint)l1 << 16);
    }
}

// ---------------------------------------------------------------------------
// K5: final linear as MFMA GEMM (unchanged).
// ---------------------------------------------------------------------------
__global__ __launch_bounds__(256) void linear_mfma_kernel(
    const ushort* __restrict__ ctx_hi, const ushort* __restrict__ ctx_lo,
    const ushort* __restrict__ w_hi, const ushort* __restrict__ w_lo,
    const float* __restrict__ bias, float* __restrict__ out)
{
    __shared__ ushort ahi[128 * 136];
    __shared__ ushort alo[128 * 136];

    int tid  = threadIdx.x;
    int lane = tid & 63, wid = tid >> 6;
    int lm = lane & 15, kb = lane >> 4;
    size_t rowbase = (size_t)blockIdx.x * 128;

    for (int idx = tid; idx < 2048; idx += 256) {
        int row = idx >> 4, c16 = idx & 15;
        short8 vh = *(const short8*)(ctx_hi + (rowbase + row) * 128 + c16 * 8);
        short8 vl = *(const short8*)(ctx_lo + (rowbase + row) * 128 + c16 * 8);
        *(short8*)(ahi + row * 136 + c16 * 8) = vh;
        *(short8*)(alo + row * 136 + c16 * 8) = vl;
    }
    __syncthreads();

    floatx4 acc[16];
#pragma unroll
    for (int i = 0; i < 16; i++) acc[i] = (floatx4){0.f, 0.f, 0.f, 0.f};

    const ushort* arow_h = ahi + (wid * 32 + lm) * 136 + kb * 8;
    const ushort* arow_l = alo + (wid * 32 + lm) * 136 + kb * 8;

#pragma unroll
    for (int kstep = 0; kstep < 4; kstep++) {
        short8 afh[2], afl[2];
#pragma unroll
        for (int mf = 0; mf < 2; mf++) {
            afh[mf] = *(const short8*)(arow_h + mf * 16 * 136 + kstep * 32);
            afl[mf] = *(const short8*)(arow_l + mf * 16 * 136 + kstep * 32);
        }
        short8 bfh[8], bfl[8];
#pragma unroll
        for (int nf = 0; nf < 8; nf++) {
            bfh[nf] = *(const short8*)(w_hi + (size_t)(nf * 16 + lm) * 128 + kstep * 32 + kb * 8);
            bfl[nf] = *(const short8*)(w_lo + (size_t)(nf * 16 + lm) * 128 + kstep * 32 + kb * 8);
        }
#pragma unroll
        for (int mf = 0; mf < 2; mf++) {
#pragma unroll
            for (int nf = 0; nf < 8; nf++) {
                int a = mf * 8 + nf;
                acc[a] = __builtin_amdgcn_mfma_f32_16x16x32_bf16(afh[mf], bfh[nf], acc[a], 0, 0, 0);
                acc[a] = __builtin_amdgcn_mfma_f32_16x16x32_bf16(afl[mf], bfh[nf], acc[a], 0, 0, 0);
                acc[a] = __builtin_amdgcn_mfma_f32_16x16x32_bf16(afh[mf], bfl[nf], acc[a], 0, 0, 0);
            }
        }
    }

#pragma unroll
    for (int nf = 0; nf < 8; nf++) {
        int col = nf * 16 + lm;
        float bv = bias[col];
#pragma unroll
        for (int mf = 0; mf < 2; mf++) {
#pragma unroll
            for (int r = 0; r < 4; r++) {
                int row = wid * 32 + mf * 16 + kb * 4 + r;
                out[(rowbase + row) * 128 + col] = acc[mf * 8 + nf][r] + bv;
            }
        }
    }
}

// ---------------------------------------------------------------------------
extern "C" void kernel_launch(void* const* d_in, const int* in_sizes, int n_in,
                              void* d_out, int out_size, void* d_ws, size_t ws_size,
                              hipStream_t stream)
{
    const float* query = (const float*)d_in[0];
    const float* key   = (const float*)d_in[1];
    const float* value = (const float*)d_in[2];
    const float* ckw   = (const float*)d_in[3];
    const float* ckb   = (const float*)d_in[4];
    const float* cvw   = (const float*)d_in[5];
    const float* cvb   = (const float*)d_in[6];
    const float* lw    = (const float*)d_in[7];
    const float* lb    = (const float*)d_in[8];
    const int*   isamp = (const int*)d_in[9];
    float* out = (float*)d_out;
    float* ws  = (float*)d_ws;

    const size_t NBSD = (size_t)B_ * S_ * D_;   // 4,194,304 floats
    float* q_h  = ws;                   // (B,H,S,DK)
    float* kbuf = ws + NBSD;            // k_rot (B,S,D); overlaid by ctx hi/lo
    float* k_h  = ws + 2 * NBSD;        // (B,H,S,DK)
    float* v_h  = ws + 3 * NBSD;        // (B,H,S,DK)
    int*   sel  = (int*)(ws + 4 * NBSD);        // (B*H, 30)
    ushort* wk_hi = (ushort*)(sel + B_ * H_ * NT_);   // [7][256][256] bf16 each
    ushort* wk_lo = wk_hi + 7 * 65536;
    ushort* wv_hi = wk_lo + 7 * 65536;
    ushort* lw_hi = wv_hi + 7 * 65536;  // [128][128]
    ushort* lw_lo = lw_hi + 16384;
    float*  trig  = (float*)(lw_lo + 16384);    // [256][64][2]
    ushort* khi_t = (ushort*)(trig + 32768);    // (B,D,S) bf16
    ushort* klo_t = khi_t + NBSD;
    ushort* vhi_t = klo_t + NBSD;
    // ctx hi/lo overlay kbuf (free after transcvt+conv)
    ushort* ctx_hi = (ushort*)kbuf;
    ushort* ctx_lo = ctx_hi + NBSD;

    wprep_kernel<<<dim3(576), 256, 0, stream>>>(ckw, cvw, lw, wk_hi, wk_lo, wv_hi, lw_hi, lw_lo);
    trig_kernel<<<dim3(64), 256, 0, stream>>>(trig);
    rotary_kernel<<<dim3((B_ * S_ * 64) / 256), 256, 0, stream>>>(query, key, trig, q_h, kbuf);
    transcvt_kernel<<<dim3(B_, 2), 256, 0, stream>>>(kbuf, value, khi_t, klo_t, vhi_t);
    conv3_kernel<<<dim3(B_, 4, 2), 256, 0, stream>>>(khi_t, klo_t, vhi_t,
                                                     wk_hi, wk_lo, wv_hi,
                                                     ckb, cvb, k_h, v_h);
    topk_kernel<<<dim3(B_ * H_), 256, 0, stream>>>(q_h, k_h, isamp, sel);
    attn_kernel<<<dim3(B_ * H_), 256, 0, stream>>>(q_h, k_h, v_h, sel, ctx_hi, ctx_lo);
    linear_mfma_kernel<<<dim3(256), 256, 0, stream>>>(ctx_hi, ctx_lo, lw_hi, lw_lo, lb, out);
}